// Round 4
// baseline (74.814 us; speedup 1.0000x reference)
//
#include <hip/hip_runtime.h>

// ARIMA_59373627900097 — round 4: single-dispatch with hierarchical
// completion-detection tail.
//
// History: R2 fusion-by-atomicAdd (4096 same-address RMW) serialized at
// ~13.7 ns/op = 50 us. R3 (2 kernels, partials in d_ws) = 66.4 us total,
// of which ~40 us is the harness's 256 MiB d_ws poison fill and only
// ~4-6 us is ours. R4 removes the second dispatch:
//   512 blocks write partial[bid], then a 2-level atomicInc tree
//   (32 counters x 16 blocks in parallel, then one chain of 32 winners)
//   elects the LAST-arriving block, which reduces the 512 partials and
//   writes the loss. Exposed RMW chain ~0.6 us (vs R2's 50 us).
// Poison-tolerance: atomicInc wrap threshold 0x40000000 — the documented
// 0xAA poison (0xAAAAAAAA >= thr) wraps to 0 on first arrival; winners
// self-reset counters to 0xAAAAAAAA so a non-poisoned consecutive call
// behaves identically. No spin, no co-residency or dispatch-order
// assumption. Release/acquire: __threadfence() around the RMW chain.

#define PP   32
#define T0V  33
#define BLK  256
#define RW   8          // windows per thread
#define SPAN (RW + 36)  // xs[k] = y[gt0+k], covers y[t+1..t+33] for all RW windows

#define NBLK   512          // fixed for S = 2^20
#define GRP1   16           // level-1 group size  -> 32 counters
#define NC1    (NBLK/GRP1)  // 32
#define WRAPV  0x40000000u  // atomicInc wrap threshold (poison >= this)
#define SENTV  0xAAAAAAAAu  // self-reset sentinel == poison

// d_ws layout (uint view): [0..511] partial floats; c1[32] at uint 1024,
// stride 32 uints (128 B, own cache line); c2 at uint 2048.
#define C1_OFF 1024
#define C1_STR 32
#define C2_OFF 2048

__global__ __launch_bounds__(BLK, 2) void arima_fused(
    const float* __restrict__ y, const float* __restrict__ arw,
    const float* __restrict__ arb, const float* __restrict__ rvw,
    const float* __restrict__ rvb, float* __restrict__ ws,
    float* __restrict__ out, int S, int T, float invS)
{
    __shared__ float red[BLK / 64];
    __shared__ int winner;

    const int tid = threadIdx.x;
    const int bid = blockIdx.x;
    const int gt0 = (bid * BLK + tid) * RW;

    // Register tile: xs[k] = y[gt0 + k]; gt0 % 8 == 0 -> aligned float4 loads.
    float xs[SPAN];
    #pragma unroll
    for (int k = 0; k < SPAN; k += 4) {
        const int gi = gt0 + k;
        if (gi + 3 < S) {
            const float4 v = *reinterpret_cast<const float4*>(y + gi);
            xs[k] = v.x; xs[k + 1] = v.y; xs[k + 2] = v.z; xs[k + 3] = v.w;
        } else {
            xs[k]     = (gi     < S) ? y[gi]     : 0.0f;
            xs[k + 1] = (gi + 1 < S) ? y[gi + 1] : 0.0f;
            xs[k + 2] = (gi + 2 < S) ? y[gi + 2] : 0.0f;
            xs[k + 3] = (gi + 3 < S) ? y[gi + 3] : 0.0f;
        }
    }

    const float rw   = rvw[0];
    const float rb   = rvb[0];
    const float bias = arb[0];
    const float w0   = arw[0];
    const float C2   = (rb * (w0 - 1.0f) + bias) / (rw + 1e-10f);

    float c[PP];   // telescoped AR coefficients (uniform -> scalar regs)
    #pragma unroll
    for (int j = 0; j < PP; ++j)
        c[j] = arw[j] - ((j < PP - 1) ? arw[j + 1] : 0.0f);

    // Rolling S1/S2 over the 8 windows; window r = xs[r+1..r+32], target xs[r+33].
    float s1 = 0.0f, s2 = 0.0f;
    #pragma unroll
    for (int k = 1; k <= PP; ++k) { const float x = xs[k]; s1 += x; s2 = fmaf(x, x, s2); }

    float val = 0.0f;
    #pragma unroll
    for (int r = 0; r < RW; ++r) {
        if (r > 0) {
            const float xo = xs[r], xn = xs[r + PP];
            s1 += xn - xo;
            s2 = fmaf(xn, xn, fmaf(-xo, xo, s2));
        }
        if (gt0 + r < T) {
            float a = 0.0f;
            #pragma unroll
            for (int j = 0; j < PP; ++j) a = fmaf(xs[r + 1 + j], c[j], a);

            const float mean  = s1 * (1.0f / PP);
            const float varp  = fmaf(-mean, mean, s2 * (1.0f / PP));
            const float stdv  = sqrtf(varp + 1e-5f);
            const float dlast = xs[r + PP] - xs[r + PP - 1];
            const float pred  = a - mean * w0 + dlast + C2 * stdv + mean;
            const float err   = xs[r + PP + 1] - pred;
            val = fmaf(err, err, val);
        }
    }

    // Head term sum(y[:33]^2) folded into block 0.
    if (bid == 0 && tid < T0V) {
        const float h = y[tid];
        val = fmaf(h, h, val);
    }

    // Block reduce: wave(64) shuffle -> cross-wave LDS.
    #pragma unroll
    for (int o = 32; o > 0; o >>= 1) val += __shfl_down(val, o, 64);
    if ((tid & 63) == 0) red[tid >> 6] = val;
    __syncthreads();

    // Completion-detection tail (thread 0).
    unsigned* wsc = reinterpret_cast<unsigned*>(ws);
    if (tid == 0) {
        ws[bid] = red[0] + red[1] + red[2] + red[3];   // partial
        __threadfence();                               // release
        int win = 0;
        const unsigned o1 = atomicInc(&wsc[C1_OFF + (bid / GRP1) * C1_STR], WRAPV);
        if (o1 == GRP1 - 2) {                          // last of my 16-group
            atomicExch(&wsc[C1_OFF + (bid / GRP1) * C1_STR], SENTV);
            __threadfence();
            const unsigned o2 = atomicInc(&wsc[C2_OFF], WRAPV);
            if (o2 == NC1 - 2) {                       // last of 32 group-winners
                atomicExch(&wsc[C2_OFF], SENTV);
                win = 1;
            }
        }
        winner = win;
    }
    __syncthreads();

    // Last-arriving block reduces all 512 partials and writes the loss.
    if (winner) {
        __threadfence();                               // acquire
        float s = 0.0f;
        #pragma unroll
        for (int i = tid; i < NBLK; i += BLK) s += ws[i];
        #pragma unroll
        for (int o = 32; o > 0; o >>= 1) s += __shfl_down(s, o, 64);
        if ((tid & 63) == 0) red[tid >> 6] = s;
        __syncthreads();
        if (tid == 0) out[0] = (red[0] + red[1] + red[2] + red[3]) * invS;
    }
}

// Fallback (generic grid size): R3's two-kernel path.
__global__ __launch_bounds__(BLK) void arima_finish(
    const float* __restrict__ partial, int nblocks,
    float* __restrict__ out, float invS)
{
    __shared__ float red[BLK / 64];
    const int tid = threadIdx.x;
    float s = 0.0f;
    for (int i = tid; i < nblocks; i += BLK) s += partial[i];
    #pragma unroll
    for (int o = 32; o > 0; o >>= 1) s += __shfl_down(s, o, 64);
    if ((tid & 63) == 0) red[tid >> 6] = s;
    __syncthreads();
    if (tid == 0) out[0] = (red[0] + red[1] + red[2] + red[3]) * invS;
}

extern "C" void kernel_launch(void* const* d_in, const int* in_sizes, int n_in,
                              void* d_out, int out_size, void* d_ws, size_t ws_size,
                              hipStream_t stream)
{
    const float* y   = (const float*)d_in[0];
    const float* arw = (const float*)d_in[1];
    const float* arb = (const float*)d_in[2];
    const float* rvw = (const float*)d_in[3];
    const float* rvb = (const float*)d_in[4];
    float* out       = (float*)d_out;
    float* ws        = (float*)d_ws;

    const int S = in_sizes[0];
    const int T = S - T0V;
    const int per_block = BLK * RW;
    const int nblocks = (T + per_block - 1) / per_block;
    const float invS = 1.0f / (float)S;

    if (nblocks == NBLK) {
        // Single-dispatch fused path (S = 2^20).
        arima_fused<<<NBLK, BLK, 0, stream>>>(y, arw, arb, rvw, rvb, ws, out,
                                              S, T, invS);
    } else {
        // Generic fallback: fused kernel would mis-detect completion; use the
        // two-kernel structure. arima_fused's tail needs exactly NBLK blocks.
        arima_fused<<<nblocks, BLK, 0, stream>>>(y, arw, arb, rvw, rvb, ws, out,
                                                 S, T, invS);  // partials only
        arima_finish<<<1, BLK, 0, stream>>>(ws, nblocks, out, invS);
    }
}

// Round 5
// 66.007 us; speedup vs baseline: 1.1334x; 1.1334x over previous
//
#include <hip/hip_runtime.h>

// ARIMA_59373627900097 — round 5: revert to the round-3 structure (measured
// best, 66.4 us total).
//
// Structure-search history (all measured on MI355X):
//   R1: 2 kernels, LDS-staged windows ............ 72.8 us (ds_read_b32 issue-bound)
//   R2: 1 kernel, 4096 same-address atomicAdd .... 114  us (atomic chain ~13.7 ns/op = 50 us)
//   R3: 2 kernels, register windows, partials->ws . 66.4 us  <-- best
//   R4: 1 kernel, fence+atomicInc completion tree . 74.8 us (per-block device-scope
//       __threadfence = cross-XCD buffer_wbl2 writeback; costs more than a dispatch)
// Conclusion: on MI355X, cross-XCD coherence ops are more expensive than an
// extra graph-node launch. Two-dispatch partials-in-d_ws is the right shape.
//
// Of R3's 66.4 us: ~40 us is the harness's 256 MiB d_ws poison fill (82% HBM
// peak, visible as fillBufferAligned in rocprof), ~20 us harness restores +
// graph gaps, ~5 us our two kernels. arima_main is within ~2x of both its
// memory floor (4 MB read = 0.7 us) and VALU-issue floor (~0.8 us).
//
// Math per window t (P=32): one register pass over xs[]:
//   S1 = sum x_j -> mean;  S2 = sum x_j^2 -> var = S2/P - mean^2
//   A  = sum x_j c_j,  c_j = w_j - w_{j+1} (w_P = 0)   [telescoped AR dot]
//   pred = A - mean*w0 + (x31-x30) + C2*std + mean,
//   C2 = (rb*(w0-1)+bias)/(rw+1e-10)    [uniform; scale/unscale cancelled]
// Each thread: RW=8 consecutive windows from a 44-float register tile
// (11 aligned float4 loads), rolling S1/S2 update between windows.

#define PP   32
#define T0V  33
#define BLK  256
#define RW   8          // windows per thread
#define SPAN (RW + 36)  // xs[k] = y[gt0+k], covers y[t+1..t+33] for all RW windows

__global__ __launch_bounds__(BLK, 2) void arima_main(
    const float* __restrict__ y, const float* __restrict__ arw,
    const float* __restrict__ arb, const float* __restrict__ rvw,
    const float* __restrict__ rvb, float* __restrict__ partial,
    int S, int T)
{
    __shared__ float red[BLK / 64];

    const int tid = threadIdx.x;
    const int gt0 = (blockIdx.x * BLK + tid) * RW;   // first window index of this thread

    // Register tile: xs[k] = y[gt0 + k]. gt0 % 8 == 0 -> 16B-aligned float4 loads.
    float xs[SPAN];
    #pragma unroll
    for (int k = 0; k < SPAN; k += 4) {
        const int gi = gt0 + k;
        if (gi + 3 < S) {
            const float4 v = *reinterpret_cast<const float4*>(y + gi);
            xs[k] = v.x; xs[k + 1] = v.y; xs[k + 2] = v.z; xs[k + 3] = v.w;
        } else {
            xs[k]     = (gi     < S) ? y[gi]     : 0.0f;
            xs[k + 1] = (gi + 1 < S) ? y[gi + 1] : 0.0f;
            xs[k + 2] = (gi + 2 < S) ? y[gi + 2] : 0.0f;
            xs[k + 3] = (gi + 3 < S) ? y[gi + 3] : 0.0f;
        }
    }

    // Uniform parameters (scalar loads) + telescoped AR coefficients.
    const float rw   = rvw[0];
    const float rb   = rvb[0];
    const float bias = arb[0];
    const float w0   = arw[0];
    const float C2   = (rb * (w0 - 1.0f) + bias) / (rw + 1e-10f);

    float c[PP];
    #pragma unroll
    for (int j = 0; j < PP; ++j)
        c[j] = arw[j] - ((j < PP - 1) ? arw[j + 1] : 0.0f);

    // Window r covers xs[r+1 .. r+32]; target xs[r+33].
    float s1 = 0.0f, s2 = 0.0f;
    #pragma unroll
    for (int k = 1; k <= PP; ++k) { const float x = xs[k]; s1 += x; s2 = fmaf(x, x, s2); }

    float val = 0.0f;
    #pragma unroll
    for (int r = 0; r < RW; ++r) {
        if (r > 0) {
            const float xo = xs[r], xn = xs[r + PP];
            s1 += xn - xo;
            s2 = fmaf(xn, xn, fmaf(-xo, xo, s2));
        }
        if (gt0 + r < T) {
            float a = 0.0f;
            #pragma unroll
            for (int j = 0; j < PP; ++j) a = fmaf(xs[r + 1 + j], c[j], a);

            const float mean  = s1 * (1.0f / PP);
            const float varp  = fmaf(-mean, mean, s2 * (1.0f / PP));
            const float stdv  = sqrtf(varp + 1e-5f);
            const float dlast = xs[r + PP] - xs[r + PP - 1];     // x31 - x30
            const float pred  = a - mean * w0 + dlast + C2 * stdv + mean;
            const float err   = xs[r + PP + 1] - pred;           // y[t+33] - pred
            val = fmaf(err, err, val);
        }
    }

    // Head term sum(y[:33]^2), folded into block 0.
    if (blockIdx.x == 0 && tid < T0V) {
        const float h = y[tid];
        val = fmaf(h, h, val);
    }

    // wave(64) shuffle reduce -> cross-wave LDS reduce -> one partial per block
    #pragma unroll
    for (int o = 32; o > 0; o >>= 1) val += __shfl_down(val, o, 64);
    if ((tid & 63) == 0) red[tid >> 6] = val;
    __syncthreads();
    if (tid == 0) partial[blockIdx.x] = red[0] + red[1] + red[2] + red[3];
}

__global__ __launch_bounds__(BLK) void arima_finish(
    const float* __restrict__ partial, int nblocks,
    float* __restrict__ out, float invS)
{
    __shared__ float red[BLK / 64];
    const int tid = threadIdx.x;

    float s = 0.0f;
    for (int i = tid; i < nblocks; i += BLK) s += partial[i];
    #pragma unroll
    for (int o = 32; o > 0; o >>= 1) s += __shfl_down(s, o, 64);
    if ((tid & 63) == 0) red[tid >> 6] = s;
    __syncthreads();
    if (tid == 0) out[0] = (red[0] + red[1] + red[2] + red[3]) * invS;
}

extern "C" void kernel_launch(void* const* d_in, const int* in_sizes, int n_in,
                              void* d_out, int out_size, void* d_ws, size_t ws_size,
                              hipStream_t stream)
{
    const float* y   = (const float*)d_in[0];
    const float* arw = (const float*)d_in[1];
    const float* arb = (const float*)d_in[2];
    const float* rvw = (const float*)d_in[3];
    const float* rvb = (const float*)d_in[4];
    float* out       = (float*)d_out;
    float* partial   = (float*)d_ws;

    const int S = in_sizes[0];
    const int T = S - T0V;
    const int per_block = BLK * RW;
    const int nblocks = (T + per_block - 1) / per_block;

    arima_main<<<nblocks, BLK, 0, stream>>>(y, arw, arb, rvw, rvb, partial, S, T);
    arima_finish<<<1, BLK, 0, stream>>>(partial, nblocks, out, 1.0f / (float)S);
}